// Round 1
// 178.617 us; speedup vs baseline: 1.0466x; 1.0466x over previous
//
#include <hip/hip_runtime.h>
#include <hip/hip_bf16.h>
#include <stdint.h>

typedef __attribute__((ext_vector_type(8))) short bf16x8;
typedef __attribute__((ext_vector_type(4))) float f32x4;

#define S_2LOG2E 2.8853900817779268f   // 2*log2(e): tanh(x)=1-2/(2^(x*S)+1)

#if __has_builtin(__builtin_amdgcn_exp2f)
#define EXP2F(x) __builtin_amdgcn_exp2f(x)
#else
#define EXP2F(x) __expf((x) * 0.6931471805599453f)
#endif
#if __has_builtin(__builtin_amdgcn_rcpf)
#define RCPF(x) __builtin_amdgcn_rcpf(x)
#else
#define RCPF(x) (1.0f / (x))
#endif

// tanh given pre-scaled argument z = S*(x) : returns tanh(x)
__device__ __forceinline__ float tanh_z(float z) {
    float e = EXP2F(z);
    float r = RCPF(e + 1.0f);
    return fmaf(-2.0f, r, 1.0f);
}
__device__ __forceinline__ float tanh_fast(float x) {   // prep only
    float e = __expf(2.0f * x);
    return 1.0f - 2.0f / (e + 1.0f);
}

// ---- bf16 pack via native v_cvt_pk_bf16_f32 (RNE) ----
__device__ __forceinline__ bf16x8 pack2(float4 a, float4 b) {
    union { bf16x8 v; __hip_bfloat162 h[4]; } r;
    r.h[0] = __float22bfloat162_rn(make_float2(a.x, a.y));
    r.h[1] = __float22bfloat162_rn(make_float2(a.z, a.w));
    r.h[2] = __float22bfloat162_rn(make_float2(b.x, b.y));
    r.h[3] = __float22bfloat162_rn(make_float2(b.z, b.w));
    return r.v;
}
__device__ __forceinline__ float4 scl4(float4 a) {      // fold S into W at cast time
    a.x *= S_2LOG2E; a.y *= S_2LOG2E; a.z *= S_2LOG2E; a.w *= S_2LOG2E;
    return a;
}
#define MFMA16(a, b, c) __builtin_amdgcn_mfma_f32_16x16x32_bf16((a), (b), (c), 0, 0, 0)

// =========================================================================
// Kernel 1 (prep), grid sections by blockIdx:
//  [0,qb)        q = tanh(user @ Wq^T + bq) -> q_ws
//  qb            bkz = S*(bk + Wk@attr), bvz = S*bv
//  (qb, qb+8]    S*Wk, S*Wv -> bf16 XOR-swizzled frag chunks -> wf_ws
//  (qb+8, qb+48] zero out (atomic target)
//  rest          item/opin tables -> bf16 chunks (1 chunk/thread now)
// =========================================================================
__global__ void finerec_prep(
    const float* __restrict__ user_emb, const float* __restrict__ attr,
    const float* __restrict__ Wq, const float* __restrict__ bq,
    const float* __restrict__ Wk, const float* __restrict__ bk,
    const float* __restrict__ Wv, const float* __restrict__ bv,
    const float* __restrict__ item_table, const float* __restrict__ opin_table,
    float* __restrict__ q_ws, float* __restrict__ bkz_ws, float* __restrict__ bvz_ws,
    short* __restrict__ wf_ws, short* __restrict__ itb, short* __restrict__ opb,
    float* __restrict__ out, int U, int n_item, int n_opi, int qb)
{
    const int bx = blockIdx.x, tid = threadIdx.x;
    if (bx >= qb + 49) {                     // ---- table cast to bf16 chunks ----
        const int castb = gridDim.x - qb - 49;
        const int gid = (bx - qb - 49) * 256 + tid;
        const int stride = castb * 256;
        const int tci = n_item * 16, tc = (n_item + n_opi) * 16;
        for (int c = gid; c < tc; c += stride) {
            if (c < tci) {
                const float* src = item_table + (size_t)c * 8;
                ((bf16x8*)itb)[c] = pack2(*(const float4*)src, *(const float4*)(src + 4));
            } else {
                const float* src = opin_table + (size_t)(c - tci) * 8;
                ((bf16x8*)opb)[c - tci] = pack2(*(const float4*)src, *(const float4*)(src + 4));
            }
        }
        return;
    }
    if (bx >= qb + 9) {                      // ---- zero the atomic output ----
        const int gid = (bx - qb - 9) * 256 + tid;
        float4 z = {0.0f, 0.0f, 0.0f, 0.0f};
        for (int i = gid; i < U * 32; i += 40 * 256) ((float4*)out)[i] = z;
        return;
    }
    if (bx >= qb + 1) {                      // ---- weight cast (pre-scaled by S) ----
        const int bi = bx - qb - 1;
#pragma unroll
        for (int t = 0; t < 2; ++t) {
            const int g = bi * 512 + t * 256 + tid;           // 0..4095
            const int mat = g >> 11, gg = g & 2047, r = gg >> 4, c = gg & 15;
            const float* src = (mat ? Wv : Wk) + r * 128 + c * 8;
            ((bf16x8*)wf_ws)[(mat << 11) + (r << 4) + (c ^ (r & 15))] =
                pack2(scl4(*(const float4*)src), scl4(*(const float4*)(src + 4)));
        }
        return;
    }
    if (bx == qb) {                          // ---- pre-scaled biases ----
        if (tid < 128) {
            const float* wr = Wk + tid * 128;
            float s = bk[tid];
            for (int k = 0; k < 128; k += 4) {
                float4 w4 = *(const float4*)(wr + k);
                float4 a4 = *(const float4*)(attr + k);
                s += w4.x * a4.x + w4.y * a4.y + w4.z * a4.z + w4.w * a4.w;
            }
            bkz_ws[tid] = s * S_2LOG2E;
        } else if (tid < 256) {
            bvz_ws[tid - 128] = bv[tid - 128] * S_2LOG2E;
        }
        return;
    }
    // ---- q: 64 users per block (16 per wave) ----
    const int wv = tid >> 6, lane = tid & 63;
    const int l15 = lane & 15, quad = lane >> 4;
    const int u0 = (bx * 4 + wv) * 16;
    int ur = u0 + l15; if (ur >= U) ur = U - 1;
    const float* up = user_emb + (size_t)ur * 128 + quad * 8;
    bf16x8 af[4];
#pragma unroll
    for (int ks = 0; ks < 4; ++ks)
        af[ks] = pack2(*(const float4*)(up + ks * 32), *(const float4*)(up + ks * 32 + 4));
#pragma unroll
    for (int nt = 0; nt < 8; ++nt) {
        const int n = nt * 16 + l15;
        const float* wp = Wq + n * 128 + quad * 8;
        f32x4 acc = {0, 0, 0, 0};
#pragma unroll
        for (int ks = 0; ks < 4; ++ks) {
            bf16x8 bf = pack2(*(const float4*)(wp + ks * 32), *(const float4*)(wp + ks * 32 + 4));
            acc = MFMA16(af[ks], bf, acc);
        }
        const float bqv = bq[n];
#pragma unroll
        for (int r = 0; r < 4; ++r) {
            int row = u0 + quad * 4 + r;
            if (row < U) q_ws[row * 128 + nt * 16 + l15] = tanh_fast(acc[r] + bqv);
        }
    }
}

// =========================================================================
// Kernel 2 (main): persistent 512x1024, launch_bounds(1024,4), 65 KB LDS
// -> 2 blocks/CU. FLATTENED row space: job = 16 consecutive (u,l) rows out
// of U*L total -> 31250 jobs (was 40000 with 14 padding rows/user = -22%).
// A job spans at most 2 users (L=50>16); 72% of jobs are single-user (fast
// path identical to before). Split jobs: per-row q via cndmask(qA,qB),
// split V-reduction (accT/accA), 4 atomics. All split bookkeeping is
// wave-uniform -> SALU. S folded into Wk/Wv at cast; pre-scaled bias sits
// in the MFMA accumulator init -> tanh_z(c) directly, no epilogue fma.
// q read per-nt from L2 (drops q_lds staging entirely).
// =========================================================================
template<int BF16, int LC>
__global__ __launch_bounds__(1024, 4) void finerec_main(
    const float* __restrict__ item_table, const float* __restrict__ opin_table,
    const int* __restrict__ item_seqs, const int* __restrict__ opin_seqs,
    const float* __restrict__ q_ws, const float* __restrict__ bkz_ws,
    const float* __restrict__ bvz_ws, const short* __restrict__ wf_ws,
    const short* __restrict__ itb, const short* __restrict__ opb,
    float* __restrict__ out, int U, int Lrt)
{
    __shared__ __align__(16) short wlds[32768];   // S*Wk + S*Wv frag chunks, XOR-swizzled
    __shared__ float bkz_lds[128], bvz_lds[128];

    const int L = LC ? LC : Lrt;                  // LC=50: compile-time magic-mul division
    const int tid = threadIdx.x;
    const int wv = tid >> 6, lane = tid & 63, l15 = lane & 15, quad = lane >> 4;

    const bf16x8* wsrc = (const bf16x8*)wf_ws;
    bf16x8* wldsv = (bf16x8*)wlds;
#pragma unroll
    for (int i = 0; i < 4; ++i)
        wldsv[i * 1024 + tid] = wsrc[i * 1024 + tid];
    if (tid < 128)      bkz_lds[tid]       = bkz_ws[tid];
    else if (tid < 256) bvz_lds[tid - 128] = bvz_ws[tid - 128];
    __syncthreads();   // the ONLY block barrier

    const int UL = U * L;
    const int njobs = (UL + 15) >> 4;
    const int nwaves = gridDim.x * 16;

#pragma unroll 1
    for (int job = blockIdx.x * 16 + wv; job < njobs; job += nwaves) {
        const int g0 = job << 4;                 // first flattened row
        const int uA = g0 / L;                   // wave-uniform -> SALU
        const int bb = L - (g0 - uA * L);        // rows of uA in this job (may be >16)
        const bool split = (bb < 16) && (uA + 1 < U);

        int vi = 0, vo = 0;
        if (lane < 16 && g0 + lane < UL) {
            vi = item_seqs[g0 + lane];
            vo = opin_seqs[g0 + lane];
        }
        const unsigned long long mb = __ballot(vi > 0);

        // ---- gather item rows -> A-frags ----
        const int idx = __shfl(vi, l15);
        bf16x8 ai[4];
        if (BF16) {
            const bf16x8* pb = (const bf16x8*)itb + (size_t)idx * 16 + quad;
#pragma unroll
            for (int ks = 0; ks < 4; ++ks) ai[ks] = pb[ks * 4];
        } else {
            const float* p = item_table + (size_t)idx * 128 + quad * 8;
#pragma unroll
            for (int ks = 0; ks < 4; ++ks)
                ai[ks] = pack2(*(const float4*)(p + ks * 32), *(const float4*)(p + ks * 32 + 4));
        }

        const float* qpA = q_ws + (size_t)uA * 128;
        float w[4] = {0, 0, 0, 0};

        // ---- K pass: c init = pre-scaled bias, W pre-scaled -> tanh_z(c) ----
        if (!split) {
#pragma unroll 1
            for (int nt = 0; nt < 8; ++nt) {
                const int n = nt * 16 + l15;
                const float qa = qpA[n];
                const float bz = bkz_lds[n];
                f32x4 c = {bz, bz, bz, bz};
#pragma unroll
                for (int ks = 0; ks < 4; ++ks)
                    c = MFMA16(ai[ks], wldsv[(n << 4) + ((ks * 4 + quad) ^ l15)], c);
#pragma unroll
                for (int r = 0; r < 4; ++r)
                    w[r] = fmaf(qa, tanh_z(c[r]), w[r]);
            }
        } else {
            const float* qpB = qpA + 128;
#pragma unroll 1
            for (int nt = 0; nt < 8; ++nt) {
                const int n = nt * 16 + l15;
                const float qa = qpA[n];
                const float qb2 = qpB[n];
                const float bz = bkz_lds[n];
                f32x4 c = {bz, bz, bz, bz};
#pragma unroll
                for (int ks = 0; ks < 4; ++ks)
                    c = MFMA16(ai[ks], wldsv[(n << 4) + ((ks * 4 + quad) ^ l15)], c);
#pragma unroll
                for (int r = 0; r < 4; ++r) {
                    const float qv = (quad * 4 + r < bb) ? qa : qb2;
                    w[r] = fmaf(qv, tanh_z(c[r]), w[r]);
                }
            }
        }
        // ---- w: reduce over 16 cols within quad + padding mask ----
#pragma unroll
        for (int r = 0; r < 4; ++r) {
            float t = w[r];
            t += __shfl_xor(t, 1); t += __shfl_xor(t, 2);
            t += __shfl_xor(t, 4); t += __shfl_xor(t, 8);
            w[r] = ((mb >> (quad * 4 + r)) & 1ull) ? t : 0.0f;
        }
        // ---- gather opin rows -> second A-frags (linearity: no add/repack) ----
        const int od = __shfl(vo, l15);
        bf16x8 ao[4];
        if (BF16) {
            const bf16x8* pb = (const bf16x8*)opb + (size_t)od * 16 + quad;
#pragma unroll
            for (int ks = 0; ks < 4; ++ks) ao[ks] = pb[ks * 4];
        } else {
            const float* p = opin_table + (size_t)od * 128 + quad * 8;
#pragma unroll
            for (int ks = 0; ks < 4; ++ks)
                ao[ks] = pack2(*(const float4*)(p + ks * 32), *(const float4*)(p + ks * 32 + 4));
        }
        // ---- V pass: c = (item + opin) @ S*Wv via chained MFMAs ----
        float* op = out + (size_t)uA * 128 + quad * 32 + l15;
        if (!split) {
            float s0 = 0.0f, s1 = 0.0f;
#pragma unroll 1
            for (int nt = 0; nt < 8; ++nt) {
                const int n = nt * 16 + l15;
                const float bz = bvz_lds[n];
                f32x4 c = {bz, bz, bz, bz};
#pragma unroll
                for (int ks = 0; ks < 4; ++ks) {
                    const bf16x8 wf = wldsv[2048 + (n << 4) + ((ks * 4 + quad) ^ l15)];
                    c = MFMA16(ai[ks], wf, c);
                    c = MFMA16(ao[ks], wf, c);
                }
                float acc = 0.0f;
#pragma unroll
                for (int r = 0; r < 4; ++r)
                    acc = fmaf(w[r], tanh_z(c[r]), acc);
                acc += __shfl_xor(acc, 16);
                acc += __shfl_xor(acc, 32);
                const bool mine = (quad == (nt >> 1));
                s0 += (mine && !(nt & 1)) ? acc : 0.0f;
                s1 += (mine &&  (nt & 1)) ? acc : 0.0f;
            }
            atomicAdd(op, s0);
            atomicAdd(op + 16, s1);
        } else {
            float sA0 = 0.0f, sA1 = 0.0f, sB0 = 0.0f, sB1 = 0.0f;
#pragma unroll 1
            for (int nt = 0; nt < 8; ++nt) {
                const int n = nt * 16 + l15;
                const float bz = bvz_lds[n];
                f32x4 c = {bz, bz, bz, bz};
#pragma unroll
                for (int ks = 0; ks < 4; ++ks) {
                    const bf16x8 wf = wldsv[2048 + (n << 4) + ((ks * 4 + quad) ^ l15)];
                    c = MFMA16(ai[ks], wf, c);
                    c = MFMA16(ao[ks], wf, c);
                }
                float accT = 0.0f, accA = 0.0f;
#pragma unroll
                for (int r = 0; r < 4; ++r) {
                    const float t = w[r] * tanh_z(c[r]);
                    accT += t;
                    accA += (quad * 4 + r < bb) ? t : 0.0f;
                }
                accT += __shfl_xor(accT, 16); accT += __shfl_xor(accT, 32);
                accA += __shfl_xor(accA, 16); accA += __shfl_xor(accA, 32);
                const float accB = accT - accA;
                const bool mine = (quad == (nt >> 1));
                const bool lo = !(nt & 1);
                sA0 += (mine && lo)  ? accA : 0.0f;
                sA1 += (mine && !lo) ? accA : 0.0f;
                sB0 += (mine && lo)  ? accB : 0.0f;
                sB1 += (mine && !lo) ? accB : 0.0f;
            }
            atomicAdd(op, sA0);
            atomicAdd(op + 16, sA1);
            atomicAdd(op + 128, sB0);        // user uA+1
            atomicAdd(op + 144, sB1);
        }
    }
}

extern "C" void kernel_launch(void* const* d_in, const int* in_sizes, int n_in,
                              void* d_out, int out_size, void* d_ws, size_t ws_size,
                              hipStream_t stream) {
    const float* item_table = (const float*)d_in[0];
    const float* opin_table = (const float*)d_in[1];
    const float* user_emb   = (const float*)d_in[2];
    const float* attr       = (const float*)d_in[3];
    const float* Wq = (const float*)d_in[4];
    const float* bq = (const float*)d_in[5];
    const float* Wk = (const float*)d_in[6];
    const float* bk = (const float*)d_in[7];
    const float* Wv = (const float*)d_in[8];
    const float* bv = (const float*)d_in[9];
    const int* item_seqs = (const int*)d_in[10];
    const int* opin_seqs = (const int*)d_in[11];
    float* out = (float*)d_out;

    const int U = in_sizes[2] / 128;        // 10000
    const int L = in_sizes[10] / U;         // 50
    const int n_item = in_sizes[0] / 128;   // 50000
    const int n_opi  = in_sizes[1] / 128;   // 5000

    // ---- ws layout ----
    char* w = (char*)d_ws;
    float* q_ws   = (float*)w;               w += (size_t)U * 128 * 4;
    float* bkz_ws = (float*)w;               w += 512;
    float* bvz_ws = (float*)w;               w += 512;
    short* wf_ws  = (short*)w;               w += 4096 * 16;
    short* itb    = (short*)w;               w += (size_t)n_item * 128 * 2;
    short* opb    = (short*)w;               w += (size_t)n_opi * 128 * 2;
    const size_t need = (size_t)(w - (char*)d_ws);
    const int use_bf16 = (ws_size >= need) ? 1 : 0;

    const int qb = (U + 63) / 64;
    // table cast: ~1 chunk/thread so prep is BW-bound, not latency-bound
    const int castb = use_bf16 ? (((n_item + n_opi) * 16 + 255) / 256) : 0;
    const int prep_grid = qb + 49 + castb;
    finerec_prep<<<prep_grid, 256, 0, stream>>>(
        user_emb, attr, Wq, bq, Wk, bk, Wv, bv, item_table, opin_table,
        q_ws, bkz_ws, bvz_ws, wf_ws, itb, opb, out, U, n_item, n_opi, qb);

    if (use_bf16) {
        if (L == 50)
            finerec_main<1, 50><<<512, 1024, 0, stream>>>(
                item_table, opin_table, item_seqs, opin_seqs,
                q_ws, bkz_ws, bvz_ws, wf_ws, itb, opb, out, U, L);
        else
            finerec_main<1, 0><<<512, 1024, 0, stream>>>(
                item_table, opin_table, item_seqs, opin_seqs,
                q_ws, bkz_ws, bvz_ws, wf_ws, itb, opb, out, U, L);
    } else {
        if (L == 50)
            finerec_main<0, 50><<<512, 1024, 0, stream>>>(
                item_table, opin_table, item_seqs, opin_seqs,
                q_ws, bkz_ws, bvz_ws, wf_ws, itb, opb, out, U, L);
        else
            finerec_main<0, 0><<<512, 1024, 0, stream>>>(
                item_table, opin_table, item_seqs, opin_seqs,
                q_ws, bkz_ws, bvz_ws, wf_ws, itb, opb, out, U, L);
    }
}